// Round 9
// baseline (376.770 us; speedup 1.0000x reference)
//
#include <hip/hip_runtime.h>

// B=4, C=12, D=32, H=128, W=128. S = D*H*W = 524288 voxels per b.
// One pass: softmax over C, accumulate 32 scalars per b, finalize 4 losses.
// HISTORY: R2 2->4 blk/CU 59->48us. R4 float2+TRANS: neutral. R6 diag: VGPR=40,
//   no spills, FETCH=106MB, VALUBusy 33%, pass2(L3)=13us vs pass1(HBM)=47us.
//   R7 bounds(256,8): spills (WRITE=62MB). R8 32 waves/CU: null. R9 2KB
//   wave-clustered bursts: null. Invariant: HBM read pattern pins ~2.3 TB/s;
//   same code from L3 ~8 TB/s; fills write 6.8 TB/s.
// R10 DIAGNOSTIC #2: discriminate H1 (memory system caps this 13-stream
//   pattern / L3-allocate policy) vs H2 (kernel load->waitcnt->compute
//   serialization). probe_plain = load-only, exact R8 geometry, cold HBM.
//   probe_nt = same but nontemporal loads, reads poison ws region (cold).
//   Sums go to dead acc slots (40/41). marg_main (R8 exact) + finalize keep
//   the round correct. Per-dispatch rocprof rows answer H1/H2.

#define S2 262144           // S/2 float2 groups per (b,c) plane
#define BLOCKS_PER_B 512
#define THREADS 256
#define ITERS 2             // 2 float2 groups (4 voxels) per thread
#define NVOX 524288.0f
#define SMOOTH 1e-5f

typedef float f32x2 __attribute__((ext_vector_type(2)));
typedef int   i32x2 __attribute__((ext_vector_type(2)));

#define WRED(v) { v += __shfl_down(v,32); v += __shfl_down(v,16); \
                  v += __shfl_down(v,8);  v += __shfl_down(v,4);  \
                  v += __shfl_down(v,2);  v += __shfl_down(v,1); }

// Per-voxel processing; COMP in {x,y}. Numerics identical to R4.
// id1 = t<=4 ? 2t+1 : t+5 ; id2 = t<=3 ? 2t+2 : -1
#define PROC2(X, TG, COMP) do {                                                \
  float xv[12];                                                                \
  _Pragma("unroll")                                                            \
  for (int c = 0; c < 12; ++c) xv[c] = X[c].COMP;                              \
  const int tgt = TG.COMP;                                                     \
  float m = xv[0];                                                             \
  _Pragma("unroll")                                                            \
  for (int c = 1; c < 12; ++c) m = fmaxf(m, xv[c]);                            \
  float e[12]; float es = 0.f;                                                 \
  _Pragma("unroll")                                                            \
  for (int c = 0; c < 12; ++c) { e[c] = __expf(xv[c] - m); es += e[c]; }       \
  const float r = __builtin_amdgcn_rcpf(es);                                   \
  float p[12];                                                                 \
  _Pragma("unroll")                                                            \
  for (int c = 0; c < 12; ++c) {                                               \
    p[c] = e[c] * r;                                                           \
    aZ[c] += p[c] * p[c];                                                      \
    aP[c] += p[c];                                                             \
  }                                                                            \
  float q = 1.f;                                                               \
  _Pragma("unroll")                                                            \
  for (int c = 1; c < 12; ++c) q = __builtin_fmaf(p[c], q, q);                 \
  const float g0 = p[0];                                                       \
  float g1 = 0.f, g2 = 0.f;                                                    \
  _Pragma("unroll")                                                            \
  for (int c = 1; c < 12; ++c) {                                               \
    if (c==1||c==3||c==5||c==7||c==9||c==10||c==11) g1 = (id1==c) ? p[c] : g1; \
    else                                            g2 = (id2==c) ? p[c] : g2; \
  }                                                                            \
  const bool t0 = (tgt == 0);                                                  \
  const bool t1 = (tgt == id1);                                                \
  const bool t2 = (tgt == id2);                                                \
  c0 += t0 ? 1.f : 0.f;  c1 += t1 ? 1.f : 0.f;  c2 += t2 ? 1.f : 0.f;          \
  p0S += t0 ? g0 : 0.f;  p1S += t1 ? g1 : 0.f;  p2S += t2 ? g2 : 0.f;          \
  const float pt = t1 ? g1 : (t2 ? g2 : 0.f);                                  \
  cesE += __logf(q * __builtin_amdgcn_rcpf(1.f + pt));                         \
  float s3 = __expf(g0) + __expf(g1);                                          \
  if (v2) s3 += __expf(g2);                                                    \
  const float gt = t0 ? g0 : (t1 ? g1 : g2);                                   \
  ces += __logf(s3) - gt;                                                      \
} while (0)

__global__ void zero_acc(float* __restrict__ acc) {
  acc[threadIdx.x] = 0.f;   // 4 b * 64 slots
}

// ---- probe 1: exact R8 load geometry, plain loads, cold HBM ----
__global__ __launch_bounds__(THREADS, 4)
void probe_plain(const f32x2* __restrict__ inp, const i32x2* __restrict__ tgp,
                 float* __restrict__ sink) {
  const int b   = blockIdx.x >> 9;        // / BLOCKS_PER_B
  const int blk = blockIdx.x & 511;
  const f32x2* inB = inp + (size_t)b * 12 * S2;
  const i32x2* tgB = tgp + (size_t)b * S2;
  float sum = 0.f;
  #pragma unroll 1
  for (int it = 0; it < ITERS; ++it) {
    const int s = blk * (ITERS * THREADS) + it * THREADS + (int)threadIdx.x;
    #pragma unroll
    for (int c = 0; c < 12; ++c) { f32x2 v = inB[c * S2 + s]; sum += v[0] + v[1]; }
    const i32x2 t = tgB[s];
    sum += (float)t[0] + (float)t[1];
  }
  WRED(sum);
  if ((threadIdx.x & 63) == 0) atomicAdd(sink, sum);
}

// ---- probe 2: same geometry, NONTEMPORAL loads, reads cold poison ws ----
__global__ __launch_bounds__(THREADS, 4)
void probe_nt(const f32x2* __restrict__ inp, const i32x2* __restrict__ tgp,
              float* __restrict__ sink) {
  const int b   = blockIdx.x >> 9;
  const int blk = blockIdx.x & 511;
  const f32x2* inB = inp + (size_t)b * 12 * S2;
  const i32x2* tgB = tgp + (size_t)b * S2;
  float sum = 0.f;
  #pragma unroll 1
  for (int it = 0; it < ITERS; ++it) {
    const int s = blk * (ITERS * THREADS) + it * THREADS + (int)threadIdx.x;
    #pragma unroll
    for (int c = 0; c < 12; ++c) {
      const f32x2 v = __builtin_nontemporal_load(&inB[c * S2 + s]);
      sum += v[0] + v[1];
    }
    const i32x2 t = __builtin_nontemporal_load(&tgB[s]);
    sum += (float)t[0] + (float)t[1];
  }
  WRED(sum);
  if ((threadIdx.x & 63) == 0) atomicAdd(sink, sum);
}

// Slot layout per b (stride 64):
//  0: ces   1: cesE   2,3,4: cnt0,cnt1,cnt2   5,6,7: pTgt0,pTgt1,pTgt2
//  8..19: z[c] = sum p_c^2    20..31: pSum[c] = sum p_c
//  slots 40,41: probe sinks (dead -- never read by finalize)
__global__ __launch_bounds__(THREADS, 4)
void marg_main(const float2* __restrict__ inp, const int2* __restrict__ tgtp,
               const int* __restrict__ task_id, float* __restrict__ acc) {
  const int b   = blockIdx.x / BLOCKS_PER_B;
  const int blk = blockIdx.x % BLOCKS_PER_B;
  const int t   = task_id[b];
  const int id1 = (t <= 4) ? 2*t + 1 : t + 5;
  const int id2 = (t <= 3) ? 2*t + 2 : -1;
  const bool v2 = (id2 >= 0);

  const float2* inB = inp  + (size_t)b * 12 * S2;
  const int2*   tgB = tgtp + (size_t)b * S2;

  float aZ[12], aP[12];
  #pragma unroll
  for (int c = 0; c < 12; ++c) { aZ[c]=0.f; aP[c]=0.f; }
  float ces=0.f, cesE=0.f, c0=0.f, c1=0.f, c2=0.f, p0S=0.f, p1S=0.f, p2S=0.f;

  #pragma unroll 1
  for (int it = 0; it < ITERS; ++it) {
    const int s = blk * (ITERS * THREADS) + it * THREADS + (int)threadIdx.x;
    float2 x[12];
    #pragma unroll
    for (int c = 0; c < 12; ++c) x[c] = inB[c * S2 + s];
    const int2 tg = tgB[s];
    PROC2(x, tg, x); PROC2(x, tg, y);
  }

  WRED(ces); WRED(cesE); WRED(c0); WRED(c1); WRED(c2);
  WRED(p0S); WRED(p1S); WRED(p2S);
  #pragma unroll
  for (int c = 0; c < 12; ++c) { WRED(aZ[c]); WRED(aP[c]); }

  __shared__ float red[4][32];
  const int lane = threadIdx.x & 63;
  const int wv   = threadIdx.x >> 6;
  if (lane == 0) {
    float* rw = red[wv];
    rw[0]=ces; rw[1]=cesE; rw[2]=c0; rw[3]=c1; rw[4]=c2;
    rw[5]=p0S; rw[6]=p1S; rw[7]=p2S;
    #pragma unroll
    for (int c = 0; c < 12; ++c) { rw[8+c]=aZ[c]; rw[20+c]=aP[c]; }
  }
  __syncthreads();
  if (threadIdx.x < 32) {
    const float sv = red[0][threadIdx.x] + red[1][threadIdx.x]
                   + red[2][threadIdx.x] + red[3][threadIdx.x];
    atomicAdd(acc + b * 64 + threadIdx.x, sv);
  }
}

__global__ void finalize(const float* __restrict__ acc,
                         const int* __restrict__ task_id,
                         float* __restrict__ out) {
  if (threadIdx.x != 0) return;
  float lmd = 0.f, lmce = 0.f, led = 0.f, lece = 0.f;
  for (int b = 0; b < 4; ++b) {
    const float* a = acc + b * 64;
    const int t   = task_id[b];
    const int id1 = (t <= 4) ? 2*t + 1 : t + 5;
    const int id2 = (t <= 3) ? 2*t + 2 : -1;

    lmce += a[0] / NVOX;
    lece += a[1] / NVOX;

    const float d0 = (2.f*a[5] + SMOOTH) / (a[8 + 0]   + a[2] + SMOOTH);
    const float d1 = (2.f*a[6] + SMOOTH) / (a[8 + id1] + a[3] + SMOOTH);
    float d2 = 1.f;
    if (id2 >= 0)
      d2 = (2.f*a[7] + SMOOTH) / (a[8 + id2] + a[4] + SMOOTH);
    lmd += (1.f - d0) + (1.f - d1) + (1.f - d2);

    led += SMOOTH / (a[8] + SMOOTH);
    for (int c = 1; c < 12; ++c) {
      const float ptc  = (c == id1) ? a[6] : ((c == id2) ? a[7] : 0.f);
      const float cntc = (c == id1) ? a[3] : ((c == id2) ? a[4] : 0.f);
      const float inter = a[20 + c] - ptc;
      const float ye    = NVOX - cntc;
      led += (2.f*inter + SMOOTH) / (a[8 + c] + ye + SMOOTH);
    }
  }
  out[0] = lmd  * 0.25f;
  out[1] = lmce * 0.25f;
  out[2] = led  * 0.25f;
  out[3] = lece * 0.25f;
}

extern "C" void kernel_launch(void* const* d_in, const int* in_sizes, int n_in,
                              void* d_out, int out_size, void* d_ws, size_t ws_size,
                              hipStream_t stream) {
  const float* inputs  = (const float*)d_in[0];
  const int*   targets = (const int*)d_in[1];
  const int*   task_id = (const int*)d_in[2];
  float* out = (float*)d_out;
  float* acc = (float*)d_ws;

  zero_acc<<<1, 256, 0, stream>>>(acc);

  // Probe 1: cold-HBM pattern BW, plain loads (input is cold: fills evicted L3)
  probe_plain<<<dim3(4 * BLOCKS_PER_B), THREADS, 0, stream>>>(
      (const f32x2*)inputs, (const i32x2*)targets, acc + 40);

  // Probe 2: NT loads over a cold poison region of the workspace (guarded).
  // Region: ws + 16MiB .. +136MiB (early-written by the poison fill, evicted
  // by the ~368MB written after it). Garbage values -> NaN sum into dead slot.
  const size_t nt_off   = (size_t)16 * 1024 * 1024;
  const size_t nt_bytes = (size_t)4 * 12 * S2 * sizeof(f32x2)   // 96 MiB
                        + (size_t)4 * S2 * sizeof(i32x2);       // + 8 MiB
  if (ws_size >= nt_off + nt_bytes + 4096) {
    const char* base = (const char*)d_ws + nt_off;
    probe_nt<<<dim3(4 * BLOCKS_PER_B), THREADS, 0, stream>>>(
        (const f32x2*)base,
        (const i32x2*)(base + (size_t)4 * 12 * S2 * sizeof(f32x2)),
        acc + 41);
  }

  marg_main<<<dim3(4 * BLOCKS_PER_B), THREADS, 0, stream>>>(
      (const float2*)inputs, (const int2*)targets, task_id, acc);
  finalize<<<1, 64, 0, stream>>>(acc, task_id, out);
}

// Round 10
// 347.431 us; speedup vs baseline: 1.0844x; 1.0844x over previous
//
#include <hip/hip_runtime.h>

// B=4, C=12, D=32, H=128, W=128. S = D*H*W = 524288 voxels per b.
// HISTORY: compute/occupancy/spill/burst theories all falsified (R4-R9).
//   Invariant: cold-HBM read ~2.3 TB/s; L3-resident full kernel ~13-15us;
//   fills write 6.8 TB/s. R10 probes were contaminated: single-address
//   atomic sink = 8192-deep serial RMW chain (~119us). Facts recovered:
//   input ~half-L3-resident across iters (fills are NT writes); marg at
//   L3 speed when warm. Best theory: per-CU outstanding-miss cap =>
//   BW = inflight*line/latency (explains L3 3.5x and all the nulls).
// R11 CLEAN PROBES (scattered sinks, ~2us tail): over COLD ws slices:
//   p_strided = exact marg geometry (anchor ~46us @2.3TB/s)
//   p_contig  = sequential float4 stream, same bytes
//       fast => pattern-specific cap (fix geometry); slow => universal
//       read roofline => marg already optimal.
//   p_nt      = strided + nontemporal loads (cache-policy lever?)
// marg_main/finalize = exact R8 (correct output).

#define S2 262144           // S/2 float2 groups per (b,c) plane
#define BLOCKS_PER_B 512
#define THREADS 256
#define ITERS 2
#define NVOX 524288.0f
#define SMOOTH 1e-5f

typedef float f32x2 __attribute__((ext_vector_type(2)));
typedef int   i32x2 __attribute__((ext_vector_type(2)));
typedef float f32x4 __attribute__((ext_vector_type(4)));

#define WRED(v) { v += __shfl_down(v,32); v += __shfl_down(v,16); \
                  v += __shfl_down(v,8);  v += __shfl_down(v,4);  \
                  v += __shfl_down(v,2);  v += __shfl_down(v,1); }

// Per-voxel processing; COMP in {x,y}. Numerics identical to R4.
#define PROC2(X, TG, COMP) do {                                                \
  float xv[12];                                                                \
  _Pragma("unroll")                                                            \
  for (int c = 0; c < 12; ++c) xv[c] = X[c].COMP;                              \
  const int tgt = TG.COMP;                                                     \
  float m = xv[0];                                                             \
  _Pragma("unroll")                                                            \
  for (int c = 1; c < 12; ++c) m = fmaxf(m, xv[c]);                            \
  float e[12]; float es = 0.f;                                                 \
  _Pragma("unroll")                                                            \
  for (int c = 0; c < 12; ++c) { e[c] = __expf(xv[c] - m); es += e[c]; }       \
  const float r = __builtin_amdgcn_rcpf(es);                                   \
  float p[12];                                                                 \
  _Pragma("unroll")                                                            \
  for (int c = 0; c < 12; ++c) {                                               \
    p[c] = e[c] * r;                                                           \
    aZ[c] += p[c] * p[c];                                                      \
    aP[c] += p[c];                                                             \
  }                                                                            \
  float q = 1.f;                                                               \
  _Pragma("unroll")                                                            \
  for (int c = 1; c < 12; ++c) q = __builtin_fmaf(p[c], q, q);                 \
  const float g0 = p[0];                                                       \
  float g1 = 0.f, g2 = 0.f;                                                    \
  _Pragma("unroll")                                                            \
  for (int c = 1; c < 12; ++c) {                                               \
    if (c==1||c==3||c==5||c==7||c==9||c==10||c==11) g1 = (id1==c) ? p[c] : g1; \
    else                                            g2 = (id2==c) ? p[c] : g2; \
  }                                                                            \
  const bool t0 = (tgt == 0);                                                  \
  const bool t1 = (tgt == id1);                                                \
  const bool t2 = (tgt == id2);                                                \
  c0 += t0 ? 1.f : 0.f;  c1 += t1 ? 1.f : 0.f;  c2 += t2 ? 1.f : 0.f;          \
  p0S += t0 ? g0 : 0.f;  p1S += t1 ? g1 : 0.f;  p2S += t2 ? g2 : 0.f;          \
  const float pt = t1 ? g1 : (t2 ? g2 : 0.f);                                  \
  cesE += __logf(q * __builtin_amdgcn_rcpf(1.f + pt));                         \
  float s3 = __expf(g0) + __expf(g1);                                          \
  if (v2) s3 += __expf(g2);                                                    \
  const float gt = t0 ? g0 : (t1 ? g1 : g2);                                   \
  ces += __logf(s3) - gt;                                                      \
} while (0)

__global__ void zero_acc(float* __restrict__ acc) {
  acc[threadIdx.x] = 0.f;   // 4 b * 64 slots
}

// ---- probe A: exact marg 13-stream geometry over cold ws slice ----
__global__ __launch_bounds__(THREADS, 4)
void p_strided(const f32x2* __restrict__ base, float* __restrict__ sink) {
  const int b = blockIdx.x >> 9, blk = blockIdx.x & 511;
  const f32x2* inB = base + (size_t)b * 13 * S2;   // 13 planes, 2MB stride
  float sum = 0.f;
  #pragma unroll 1
  for (int it = 0; it < ITERS; ++it) {
    const int s = blk * (ITERS * THREADS) + it * THREADS + (int)threadIdx.x;
    #pragma unroll
    for (int c = 0; c < 13; ++c) { f32x2 v = inB[(size_t)c * S2 + s]; sum += v[0] + v[1]; }
  }
  WRED(sum);
  if ((threadIdx.x & 63) == 0) atomicAdd(&sink[blockIdx.x & 63], sum);
}

// ---- probe B: sequential float4 stream, same total bytes ----
__global__ __launch_bounds__(THREADS, 4)
void p_contig(const f32x4* __restrict__ base, float* __restrict__ sink) {
  const int gtid = blockIdx.x * THREADS + (int)threadIdx.x;  // 524288 threads
  float sum = 0.f;
  #pragma unroll 1
  for (int i = 0; i < 13; ++i) {
    const f32x4 v = base[(size_t)i * 524288 + gtid];
    sum += v[0] + v[1] + v[2] + v[3];
  }
  WRED(sum);
  if ((threadIdx.x & 63) == 0) atomicAdd(&sink[blockIdx.x & 63], sum);
}

// ---- probe C: strided geometry + nontemporal loads ----
__global__ __launch_bounds__(THREADS, 4)
void p_nt(const f32x2* __restrict__ base, float* __restrict__ sink) {
  const int b = blockIdx.x >> 9, blk = blockIdx.x & 511;
  const f32x2* inB = base + (size_t)b * 13 * S2;
  float sum = 0.f;
  #pragma unroll 1
  for (int it = 0; it < ITERS; ++it) {
    const int s = blk * (ITERS * THREADS) + it * THREADS + (int)threadIdx.x;
    #pragma unroll
    for (int c = 0; c < 13; ++c) {
      const f32x2 v = __builtin_nontemporal_load(&inB[(size_t)c * S2 + s]);
      sum += v[0] + v[1];
    }
  }
  WRED(sum);
  if ((threadIdx.x & 63) == 0) atomicAdd(&sink[blockIdx.x & 63], sum);
}

// Slot layout per b (stride 64): 0..31 as before. Probe sinks live at
// d_ws + 1KB (floats 256..319) -- never read by finalize.
__global__ __launch_bounds__(THREADS, 4)
void marg_main(const float2* __restrict__ inp, const int2* __restrict__ tgtp,
               const int* __restrict__ task_id, float* __restrict__ acc) {
  const int b   = blockIdx.x / BLOCKS_PER_B;
  const int blk = blockIdx.x % BLOCKS_PER_B;
  const int t   = task_id[b];
  const int id1 = (t <= 4) ? 2*t + 1 : t + 5;
  const int id2 = (t <= 3) ? 2*t + 2 : -1;
  const bool v2 = (id2 >= 0);

  const float2* inB = inp  + (size_t)b * 12 * S2;
  const int2*   tgB = tgtp + (size_t)b * S2;

  float aZ[12], aP[12];
  #pragma unroll
  for (int c = 0; c < 12; ++c) { aZ[c]=0.f; aP[c]=0.f; }
  float ces=0.f, cesE=0.f, c0=0.f, c1=0.f, c2=0.f, p0S=0.f, p1S=0.f, p2S=0.f;

  #pragma unroll 1
  for (int it = 0; it < ITERS; ++it) {
    const int s = blk * (ITERS * THREADS) + it * THREADS + (int)threadIdx.x;
    float2 x[12];
    #pragma unroll
    for (int c = 0; c < 12; ++c) x[c] = inB[c * S2 + s];
    const int2 tg = tgB[s];
    PROC2(x, tg, x); PROC2(x, tg, y);
  }

  WRED(ces); WRED(cesE); WRED(c0); WRED(c1); WRED(c2);
  WRED(p0S); WRED(p1S); WRED(p2S);
  #pragma unroll
  for (int c = 0; c < 12; ++c) { WRED(aZ[c]); WRED(aP[c]); }

  __shared__ float red[4][32];
  const int lane = threadIdx.x & 63;
  const int wv   = threadIdx.x >> 6;
  if (lane == 0) {
    float* rw = red[wv];
    rw[0]=ces; rw[1]=cesE; rw[2]=c0; rw[3]=c1; rw[4]=c2;
    rw[5]=p0S; rw[6]=p1S; rw[7]=p2S;
    #pragma unroll
    for (int c = 0; c < 12; ++c) { rw[8+c]=aZ[c]; rw[20+c]=aP[c]; }
  }
  __syncthreads();
  if (threadIdx.x < 32) {
    const float sv = red[0][threadIdx.x] + red[1][threadIdx.x]
                   + red[2][threadIdx.x] + red[3][threadIdx.x];
    atomicAdd(acc + b * 64 + threadIdx.x, sv);
  }
}

__global__ void finalize(const float* __restrict__ acc,
                         const int* __restrict__ task_id,
                         float* __restrict__ out) {
  if (threadIdx.x != 0) return;
  float lmd = 0.f, lmce = 0.f, led = 0.f, lece = 0.f;
  for (int b = 0; b < 4; ++b) {
    const float* a = acc + b * 64;
    const int t   = task_id[b];
    const int id1 = (t <= 4) ? 2*t + 1 : t + 5;
    const int id2 = (t <= 3) ? 2*t + 2 : -1;

    lmce += a[0] / NVOX;
    lece += a[1] / NVOX;

    const float d0 = (2.f*a[5] + SMOOTH) / (a[8 + 0]   + a[2] + SMOOTH);
    const float d1 = (2.f*a[6] + SMOOTH) / (a[8 + id1] + a[3] + SMOOTH);
    float d2 = 1.f;
    if (id2 >= 0)
      d2 = (2.f*a[7] + SMOOTH) / (a[8 + id2] + a[4] + SMOOTH);
    lmd += (1.f - d0) + (1.f - d1) + (1.f - d2);

    led += SMOOTH / (a[8] + SMOOTH);
    for (int c = 1; c < 12; ++c) {
      const float ptc  = (c == id1) ? a[6] : ((c == id2) ? a[7] : 0.f);
      const float cntc = (c == id1) ? a[3] : ((c == id2) ? a[4] : 0.f);
      const float inter = a[20 + c] - ptc;
      const float ye    = NVOX - cntc;
      led += (2.f*inter + SMOOTH) / (a[8 + c] + ye + SMOOTH);
    }
  }
  out[0] = lmd  * 0.25f;
  out[1] = lmce * 0.25f;
  out[2] = led  * 0.25f;
  out[3] = lece * 0.25f;
}

extern "C" void kernel_launch(void* const* d_in, const int* in_sizes, int n_in,
                              void* d_out, int out_size, void* d_ws, size_t ws_size,
                              hipStream_t stream) {
  const float* inputs  = (const float*)d_in[0];
  const int*   targets = (const int*)d_in[1];
  const int*   task_id = (const int*)d_in[2];
  float* out = (float*)d_out;
  float* acc = (float*)d_ws;
  float* sink = (float*)d_ws + 256;   // dead scratch, never read

  zero_acc<<<1, 256, 0, stream>>>(acc);

  // Cold slices of the NT-poisoned workspace. SLICE = 4*13*S2*8B = 104 MiB.
  const size_t SLICE  = (size_t)4 * 13 * S2 * sizeof(f32x2);
  const size_t OFS0   = (size_t)16 * 1024 * 1024;
  const char*  wsb    = (const char*)d_ws;
  const bool   three  = (ws_size >= OFS0 + 3 * SLICE + 4096);
  const bool   one    = (ws_size >= OFS0 + SLICE + 4096);
  if (one) {
    const char* s0 = wsb + OFS0;
    const char* s1 = three ? (wsb + OFS0 + SLICE)     : s0;
    const char* s2 = three ? (wsb + OFS0 + 2 * SLICE) : s0;
    p_strided<<<dim3(4 * BLOCKS_PER_B), THREADS, 0, stream>>>((const f32x2*)s0, sink);
    p_contig <<<dim3(4 * BLOCKS_PER_B), THREADS, 0, stream>>>((const f32x4*)s1, sink);
    p_nt     <<<dim3(4 * BLOCKS_PER_B), THREADS, 0, stream>>>((const f32x2*)s2, sink);
  }

  marg_main<<<dim3(4 * BLOCKS_PER_B), THREADS, 0, stream>>>(
      (const float2*)inputs, (const int2*)targets, task_id, acc);
  finalize<<<1, 64, 0, stream>>>(acc, task_id, out);
}

// Round 11
// 236.855 us; speedup vs baseline: 1.5907x; 1.4668x over previous
//
#include <hip/hip_runtime.h>

// B=4, C=12, D=32, H=128, W=128. S = D*H*W = 524288 voxels per b.
// HISTORY: compute/occupancy/spill/burst/NT theories all falsified (R4-R11).
//   Facts: any read shape with MLP 6-14/wave = ~2.1-2.3 TB/s cold-ish;
//   L3-served = ~8 TB/s; fills write 6.8 TB/s; poison leaves ~half of any
//   buffer L3-warm (FETCH 53MB per 104MB "cold" read). R11's p_contig (80us)
//   was an MLP=1 latency chain (unroll-1 + dependent sum) -- my bug.
// R12 FINAL DISCRIMINATOR: p_sweep = canonical max-BW read (m13-style):
//   sequential grid-stride float4 sweep, unroll 8, 8 INDEPENDENT sums
//   (8 loads in flight, no vmcnt(0) drain between groups), scattered sinks.
//   If ~2.3 TB/s => universal read cap => marg has been at roofline since
//   R2 => declare. If 4-6 TB/s => restructure marg to sweep shape.
// marg_main/finalize = exact R8 (correct output, 167us baseline behavior).

#define S2 262144           // S/2 float2 groups per (b,c) plane
#define BLOCKS_PER_B 512
#define THREADS 256
#define ITERS 2
#define NVOX 524288.0f
#define SMOOTH 1e-5f

typedef float f32x4 __attribute__((ext_vector_type(4)));

#define WRED(v) { v += __shfl_down(v,32); v += __shfl_down(v,16); \
                  v += __shfl_down(v,8);  v += __shfl_down(v,4);  \
                  v += __shfl_down(v,2);  v += __shfl_down(v,1); }

// Per-voxel processing; COMP in {x,y}. Numerics identical to R4.
#define PROC2(X, TG, COMP) do {                                                \
  float xv[12];                                                                \
  _Pragma("unroll")                                                            \
  for (int c = 0; c < 12; ++c) xv[c] = X[c].COMP;                              \
  const int tgt = TG.COMP;                                                     \
  float m = xv[0];                                                             \
  _Pragma("unroll")                                                            \
  for (int c = 1; c < 12; ++c) m = fmaxf(m, xv[c]);                            \
  float e[12]; float es = 0.f;                                                 \
  _Pragma("unroll")                                                            \
  for (int c = 0; c < 12; ++c) { e[c] = __expf(xv[c] - m); es += e[c]; }       \
  const float r = __builtin_amdgcn_rcpf(es);                                   \
  float p[12];                                                                 \
  _Pragma("unroll")                                                            \
  for (int c = 0; c < 12; ++c) {                                               \
    p[c] = e[c] * r;                                                           \
    aZ[c] += p[c] * p[c];                                                      \
    aP[c] += p[c];                                                             \
  }                                                                            \
  float q = 1.f;                                                               \
  _Pragma("unroll")                                                            \
  for (int c = 1; c < 12; ++c) q = __builtin_fmaf(p[c], q, q);                 \
  const float g0 = p[0];                                                       \
  float g1 = 0.f, g2 = 0.f;                                                    \
  _Pragma("unroll")                                                            \
  for (int c = 1; c < 12; ++c) {                                               \
    if (c==1||c==3||c==5||c==7||c==9||c==10||c==11) g1 = (id1==c) ? p[c] : g1; \
    else                                            g2 = (id2==c) ? p[c] : g2; \
  }                                                                            \
  const bool t0 = (tgt == 0);                                                  \
  const bool t1 = (tgt == id1);                                                \
  const bool t2 = (tgt == id2);                                                \
  c0 += t0 ? 1.f : 0.f;  c1 += t1 ? 1.f : 0.f;  c2 += t2 ? 1.f : 0.f;          \
  p0S += t0 ? g0 : 0.f;  p1S += t1 ? g1 : 0.f;  p2S += t2 ? g2 : 0.f;          \
  const float pt = t1 ? g1 : (t2 ? g2 : 0.f);                                  \
  cesE += __logf(q * __builtin_amdgcn_rcpf(1.f + pt));                         \
  float s3 = __expf(g0) + __expf(g1);                                          \
  if (v2) s3 += __expf(g2);                                                    \
  const float gt = t0 ? g0 : (t1 ? g1 : g2);                                   \
  ces += __logf(s3) - gt;                                                      \
} while (0)

__global__ void zero_acc(float* __restrict__ acc) {
  acc[threadIdx.x] = 0.f;   // 4 b * 64 slots
}

// ---- p_sweep: canonical max-BW read probe ----
// 192 MiB = 12582912 float4; 524288 threads -> 24 float4/thread.
// Grid-stride: idx = gtid + i*524288. unroll 8, 8 independent sums.
__global__ __launch_bounds__(THREADS, 4)
void p_sweep(const f32x4* __restrict__ base, float* __restrict__ sink) {
  const int gtid = blockIdx.x * THREADS + (int)threadIdx.x;
  float s0=0.f, s1=0.f, s2=0.f, s3=0.f, s4=0.f, s5=0.f, s6=0.f, s7=0.f;
  #pragma unroll 8
  for (int i = 0; i < 24; ++i) {
    const f32x4 v = base[(size_t)i * 524288 + gtid];
    switch (i & 7) {
      case 0: s0 += v[0]+v[1]+v[2]+v[3]; break;
      case 1: s1 += v[0]+v[1]+v[2]+v[3]; break;
      case 2: s2 += v[0]+v[1]+v[2]+v[3]; break;
      case 3: s3 += v[0]+v[1]+v[2]+v[3]; break;
      case 4: s4 += v[0]+v[1]+v[2]+v[3]; break;
      case 5: s5 += v[0]+v[1]+v[2]+v[3]; break;
      case 6: s6 += v[0]+v[1]+v[2]+v[3]; break;
      default: s7 += v[0]+v[1]+v[2]+v[3]; break;
    }
  }
  float sum = ((s0+s1)+(s2+s3)) + ((s4+s5)+(s6+s7));
  WRED(sum);
  if ((threadIdx.x & 63) == 0) atomicAdd(&sink[blockIdx.x & 63], sum);
}

// Slot layout per b (stride 64): 0..31 as before; sinks at ws floats 256+.
__global__ __launch_bounds__(THREADS, 4)
void marg_main(const float2* __restrict__ inp, const int2* __restrict__ tgtp,
               const int* __restrict__ task_id, float* __restrict__ acc) {
  const int b   = blockIdx.x / BLOCKS_PER_B;
  const int blk = blockIdx.x % BLOCKS_PER_B;
  const int t   = task_id[b];
  const int id1 = (t <= 4) ? 2*t + 1 : t + 5;
  const int id2 = (t <= 3) ? 2*t + 2 : -1;
  const bool v2 = (id2 >= 0);

  const float2* inB = inp  + (size_t)b * 12 * S2;
  const int2*   tgB = tgtp + (size_t)b * S2;

  float aZ[12], aP[12];
  #pragma unroll
  for (int c = 0; c < 12; ++c) { aZ[c]=0.f; aP[c]=0.f; }
  float ces=0.f, cesE=0.f, c0=0.f, c1=0.f, c2=0.f, p0S=0.f, p1S=0.f, p2S=0.f;

  #pragma unroll 1
  for (int it = 0; it < ITERS; ++it) {
    const int s = blk * (ITERS * THREADS) + it * THREADS + (int)threadIdx.x;
    float2 x[12];
    #pragma unroll
    for (int c = 0; c < 12; ++c) x[c] = inB[c * S2 + s];
    const int2 tg = tgB[s];
    PROC2(x, tg, x); PROC2(x, tg, y);
  }

  WRED(ces); WRED(cesE); WRED(c0); WRED(c1); WRED(c2);
  WRED(p0S); WRED(p1S); WRED(p2S);
  #pragma unroll
  for (int c = 0; c < 12; ++c) { WRED(aZ[c]); WRED(aP[c]); }

  __shared__ float red[4][32];
  const int lane = threadIdx.x & 63;
  const int wv   = threadIdx.x >> 6;
  if (lane == 0) {
    float* rw = red[wv];
    rw[0]=ces; rw[1]=cesE; rw[2]=c0; rw[3]=c1; rw[4]=c2;
    rw[5]=p0S; rw[6]=p1S; rw[7]=p2S;
    #pragma unroll
    for (int c = 0; c < 12; ++c) { rw[8+c]=aZ[c]; rw[20+c]=aP[c]; }
  }
  __syncthreads();
  if (threadIdx.x < 32) {
    const float sv = red[0][threadIdx.x] + red[1][threadIdx.x]
                   + red[2][threadIdx.x] + red[3][threadIdx.x];
    atomicAdd(acc + b * 64 + threadIdx.x, sv);
  }
}

__global__ void finalize(const float* __restrict__ acc,
                         const int* __restrict__ task_id,
                         float* __restrict__ out) {
  if (threadIdx.x != 0) return;
  float lmd = 0.f, lmce = 0.f, led = 0.f, lece = 0.f;
  for (int b = 0; b < 4; ++b) {
    const float* a = acc + b * 64;
    const int t   = task_id[b];
    const int id1 = (t <= 4) ? 2*t + 1 : t + 5;
    const int id2 = (t <= 3) ? 2*t + 2 : -1;

    lmce += a[0] / NVOX;
    lece += a[1] / NVOX;

    const float d0 = (2.f*a[5] + SMOOTH) / (a[8 + 0]   + a[2] + SMOOTH);
    const float d1 = (2.f*a[6] + SMOOTH) / (a[8 + id1] + a[3] + SMOOTH);
    float d2 = 1.f;
    if (id2 >= 0)
      d2 = (2.f*a[7] + SMOOTH) / (a[8 + id2] + a[4] + SMOOTH);
    lmd += (1.f - d0) + (1.f - d1) + (1.f - d2);

    led += SMOOTH / (a[8] + SMOOTH);
    for (int c = 1; c < 12; ++c) {
      const float ptc  = (c == id1) ? a[6] : ((c == id2) ? a[7] : 0.f);
      const float cntc = (c == id1) ? a[3] : ((c == id2) ? a[4] : 0.f);
      const float inter = a[20 + c] - ptc;
      const float ye    = NVOX - cntc;
      led += (2.f*inter + SMOOTH) / (a[8 + c] + ye + SMOOTH);
    }
  }
  out[0] = lmd  * 0.25f;
  out[1] = lmce * 0.25f;
  out[2] = led  * 0.25f;
  out[3] = lece * 0.25f;
}

extern "C" void kernel_launch(void* const* d_in, const int* in_sizes, int n_in,
                              void* d_out, int out_size, void* d_ws, size_t ws_size,
                              hipStream_t stream) {
  const float* inputs  = (const float*)d_in[0];
  const int*   targets = (const int*)d_in[1];
  const int*   task_id = (const int*)d_in[2];
  float* out = (float*)d_out;
  float* acc = (float*)d_ws;
  float* sink = (float*)d_ws + 256;   // dead scratch, never read by finalize

  zero_acc<<<1, 256, 0, stream>>>(acc);

  // p_sweep over a 192 MiB ws slice at +16 MiB (poison-written each iter).
  const size_t OFS0  = (size_t)16 * 1024 * 1024;
  const size_t BYTES = (size_t)192 * 1024 * 1024;
  if (ws_size >= OFS0 + BYTES + 4096) {
    p_sweep<<<dim3(4 * BLOCKS_PER_B), THREADS, 0, stream>>>(
        (const f32x4*)((const char*)d_ws + OFS0), sink);
  }

  marg_main<<<dim3(4 * BLOCKS_PER_B), THREADS, 0, stream>>>(
      (const float2*)inputs, (const int2*)targets, task_id, acc);
  finalize<<<1, 64, 0, stream>>>(acc, task_id, out);
}